// Round 7
// baseline (410.812 us; speedup 1.0000x reference)
//
#include <hip/hip_runtime.h>
#include <math.h>

#define B 128
#define T 1024
#define H 256
#define L 16
#define INV_TEMP (1.0f/0.07f)
#define NEG_INF -1e30f

// ws layout (only seg<nseg regions are ever written/read -> no memset):
//   ws_pp   : float[B][4][L][H]   per-seg prototype partial sums   8 MB
//   ws_cntp : int[B][4][L]        per-seg label counts             32 KB

// ---------------------------------------------------------------------------
// Kernel 1 (v5, unchanged — proven at ~16 us): GATHER formulation.
// Counting-sort tokens by label into LDS index lists, then each thread owns
// (label l, float4 column cs) and gathers the cnt[l] member rows from global
// into a register accumulator. grid = B*4 segs*4 chunks = 2048 blocks.
__global__ __launch_bounds__(256) void proto_kernel(
    const float* __restrict__ feat, const int* __restrict__ dlen,
    const int* __restrict__ labels, float* __restrict__ ws_pp,
    int* __restrict__ ws_cntp, float* __restrict__ out) {
  __shared__ int idx[L][256];   // 16 KB: token lists per label
  __shared__ int cnt[L];

  const int bx = blockIdx.x;
  if (bx == 0 && threadIdx.x == 0) out[0] = 0.f;   // replaces memset dispatch

  const int b = bx >> 4;
  const int seg = (bx >> 2) & 3;
  const int ch = bx & 3;          // 64-float chunk of H
  const int tid = threadIdx.x;

  const int len = dlen[b];
  if (seg * 256 >= len) return;   // uniform exit, before any barrier
  int segLen = len - seg * 256;
  if (segLen > 256) segLen = 256;

  if (tid < L) cnt[tid] = 0;
  __syncthreads();
  if (tid < segLen) {
    const int l = labels[(size_t)b * T + seg * 256 + tid];
    const int p = atomicAdd(&cnt[l], 1);   // 256 int atomics total: cheap
    idx[l][p] = tid;
  }
  __syncthreads();

  const int l = tid >> 4;         // owned label
  const int cs = tid & 15;        // owned float4 within the 64-float chunk
  const float4* fb4 = (const float4*)feat +
      ((size_t)b * T + seg * 256) * (H / 4) + ch * 16 + cs;

  const int c = cnt[l];
  float4 a = make_float4(0.f, 0.f, 0.f, 0.f);
  int i = 0;
  for (; i + 8 <= c; i += 8) {    // 8 independent loads in flight
    int t8[8];
#pragma unroll
    for (int u = 0; u < 8; ++u) t8[u] = idx[l][i + u];
    float4 f8[8];
#pragma unroll
    for (int u = 0; u < 8; ++u) f8[u] = fb4[(size_t)t8[u] * (H / 4)];
#pragma unroll
    for (int u = 0; u < 8; ++u) {
      a.x += f8[u].x; a.y += f8[u].y; a.z += f8[u].z; a.w += f8[u].w;
    }
  }
  for (; i < c; ++i) {
    const float4 f = fb4[(size_t)idx[l][i] * (H / 4)];
    a.x += f.x; a.y += f.y; a.z += f.z; a.w += f.w;
  }

  *(float4*)(ws_pp + (((size_t)b * 4 + seg) * L + l) * H + ch * 64 + cs * 4) = a;
  if (ch == 0 && tid < L) ws_cntp[(b * 4 + seg) * L + tid] = cnt[tid];
}

// ---------------------------------------------------------------------------
// Kernel 2 (v7): fused dots+loss, 4-token pr-read sharing.
// Block = 256-token quarter, 256 thr = (ts in [0,64), qh = wave = H-quarter).
// Thread computes dot[4][L] for tokens q*256 + j*64 + ts (j<kmax) over its
// 64-float H-quarter: each wave-uniform pr ds_read_b128 feeds 4 tokens ->
// 16 FMA/read (2x R5, DS issue halved). Cross-quarter combine via padded
// LDS part[3][256][17] (scalar b32: 2 lanes/bank, conflict-free). cb=0
// feature batch prefetched BEFORE pr staging (latency hides under staging).
// kmax gives uniform 64-token-granularity skip of dead token groups.
#define LOADB(BUF, CB)                                                     \
  _Pragma("unroll") for (int j = 0; j < 4; ++j) {                          \
    if (j < kmax) {                                                        \
      _Pragma("unroll") for (int u = 0; u < 4; ++u)                        \
        BUF[j][u] = fj[j][(CB) * 4 + u];                                   \
    }                                                                      \
  }
#define FMAB(BUF, CB)                                                      \
  _Pragma("unroll") for (int q4 = 0; q4 < 4; ++q4) {                       \
    _Pragma("unroll") for (int l = 0; l < L; ++l) {                        \
      const float4 p =                                                     \
          *(const float4*)&pr[l * H + qh * 64 + (CB) * 16 + q4 * 4];       \
      _Pragma("unroll") for (int j = 0; j < 4; ++j) {                      \
        if (j < kmax) {                                                    \
          dot[j][l] += BUF[j][q4].x * p.x + BUF[j][q4].y * p.y +           \
                       BUF[j][q4].z * p.z + BUF[j][q4].w * p.w;            \
        }                                                                  \
      }                                                                    \
    }                                                                      \
  }

__global__ __launch_bounds__(256, 2) void dotsloss_kernel(
    const float* __restrict__ feat, const int* __restrict__ dlen,
    const int* __restrict__ labels, const float* __restrict__ ws_pp,
    const int* __restrict__ ws_cntp, float* __restrict__ out) {
  __shared__ float pr[L * H];          // 16 KB prototypes, full H
  __shared__ float part[3][256][L + 1];// 52.2 KB padded cross-quarter partials
  __shared__ int cnts[L];

  const int b = blockIdx.x >> 2;
  const int q = blockIdx.x & 3;        // 256-token quarter
  const int tid = threadIdx.x;

  const int len = dlen[b];
  if (q * 256 >= len) return;          // uniform exit
  const int nseg = (len + 255) >> 8;
  int kmax = (len - q * 256 + 63) >> 6;   // active 64-token groups, 1..4
  if (kmax > 4) kmax = 4;

  const int ts = tid & 63;
  const int qh = tid >> 6;             // wave index == H-quarter (uniform)

  // per-j feature base: token t = q*256 + j*64 + ts, quarter qh
  const float4* fj[4];
#pragma unroll
  for (int j = 0; j < 4; ++j) {
    const int t = q * 256 + j * 64 + ts;   // always < T: loads safe
    fj[j] = (const float4*)(feat + ((size_t)b * T + t) * H) + qh * 16;
  }

  // EARLY prefetch of cb=0 batch: latency hides under cnts + pr staging
  float4 bufA[4][4], bufB[4][4];
  LOADB(bufA, 0);

  if (tid < L) {
    const int* cp = ws_cntp + b * 4 * L + tid;
    int c = 0;
    for (int s = 0; s < nseg; ++s) c += cp[s * L];
    cnts[tid] = c;
  }
  __syncthreads();

  // assemble prototypes (full H): sum valid segment partials, divide by count
  const float4* gp4 = (const float4*)(ws_pp + (size_t)b * 4 * L * H);
  for (int i = tid; i < L * H / 4; i += 256) {   // 1024 float4, 4 iters
    const int l = i >> 6;                        // 64 float4 per label row
    float4 s = gp4[i];                           // nseg >= 1 always
    for (int sg = 1; sg < nseg; ++sg) {
      const float4 t2 = gp4[sg * (L * 64) + i];
      s.x += t2.x; s.y += t2.y; s.z += t2.z; s.w += t2.w;
    }
    const int cn = cnts[l];
    const float inv = (cn > 0) ? 1.f / (float)cn : 0.f;
    ((float4*)pr)[i] = make_float4(s.x * inv, s.y * inv, s.z * inv, s.w * inv);
  }
  __syncthreads();

  float dot[4][L];
#pragma unroll
  for (int j = 0; j < 4; ++j)
#pragma unroll
    for (int l = 0; l < L; ++l) dot[j][l] = 0.f;

  // 4 cb chunks of 16 floats; explicit ping-pong, one batch always in flight
  LOADB(bufB, 1); FMAB(bufA, 0);
  LOADB(bufA, 2); FMAB(bufB, 1);
  LOADB(bufB, 3); FMAB(bufA, 2);
  FMAB(bufB, 3);

  // publish quarters 1..3 (scalar b32: bank = (r*17+l)%32, 2 lanes/bank)
  if (qh != 0) {
#pragma unroll
    for (int j = 0; j < 4; ++j) {
      if (j < kmax) {
#pragma unroll
        for (int l = 0; l < L; ++l) part[qh - 1][j * 64 + ts][l] = dot[j][l];
      }
    }
  }
  __syncthreads();

  if (qh == 0) {
    float tok = 0.f;
#pragma unroll
    for (int j = 0; j < 4; ++j) {
      if (j < kmax) {
        const int t = q * 256 + j * 64 + ts;
        if (t < len) {
          float lg[L];
#pragma unroll
          for (int l = 0; l < L; ++l) {
            const float d = dot[j][l] + part[0][j * 64 + ts][l] +
                            part[1][j * 64 + ts][l] + part[2][j * 64 + ts][l];
            lg[l] = (cnts[l] > 0) ? d * INV_TEMP : NEG_INF;
          }
          float m = lg[0];
#pragma unroll
          for (int l = 1; l < L; ++l) m = fmaxf(m, lg[l]);
          float se = 0.f;
#pragma unroll
          for (int l = 0; l < L; ++l) se += expf(lg[l] - m);
          const float lsp = m + logf(se);

          const int lab = labels[(size_t)b * T + t];
          float pos = 0.f;
#pragma unroll
          for (int l = 0; l < L; ++l) pos += (l == lab) ? lg[l] : 0.f;

          tok += lsp - pos;
        }
      }
    }
    // wave-0 shuffle reduction; single atomic per block
    float v = tok;
#pragma unroll
    for (int off = 32; off > 0; off >>= 1) v += __shfl_down(v, off, 64);
    if (ts == 0) atomicAdd(out, v / ((float)len * (float)B));
  }
}

extern "C" void kernel_launch(void* const* d_in, const int* in_sizes, int n_in,
                              void* d_out, int out_size, void* d_ws, size_t ws_size,
                              hipStream_t stream) {
  const float* feat = (const float*)d_in[0];
  const int* dlen = (const int*)d_in[1];
  const int* labels = (const int*)d_in[2];
  float* out = (float*)d_out;

  float* ws_pp = (float*)d_ws;                           // B*4*L*H floats
  int* ws_cntp = (int*)(ws_pp + (size_t)B * 4 * L * H);  // B*4*L ints

  proto_kernel<<<B * 16, 256, 0, stream>>>(feat, dlen, labels, ws_pp,
                                           ws_cntp, out);
  dotsloss_kernel<<<B * 4, 256, 0, stream>>>(feat, dlen, labels, ws_pp,
                                             ws_cntp, out);
}

// Round 8
// 271.050 us; speedup vs baseline: 1.5156x; 1.5156x over previous
//
#include <hip/hip_runtime.h>
#include <math.h>

#define B 128
#define T 1024
#define H 256
#define L 16
#define INV_TEMP (1.0f/0.07f)
#define NEG_INF -1e30f

// ws layout (only seg<nseg regions are ever written/read -> no memset):
//   ws_pp   : float[B][4][L][H]   per-seg prototype partial sums   8 MB
//   ws_cntp : int[B][4][L]        per-seg label counts             32 KB

// ---------------------------------------------------------------------------
// Kernel 1 (v5, unchanged — proven ~16 us): GATHER formulation.
// Counting-sort tokens by label into LDS index lists, then each thread owns
// (label l, float4 column cs) and gathers the cnt[l] member rows from global
// into a register accumulator. grid = B*4 segs*4 chunks = 2048 blocks.
__global__ __launch_bounds__(256) void proto_kernel(
    const float* __restrict__ feat, const int* __restrict__ dlen,
    const int* __restrict__ labels, float* __restrict__ ws_pp,
    int* __restrict__ ws_cntp, float* __restrict__ out) {
  __shared__ int idx[L][256];   // 16 KB: token lists per label
  __shared__ int cnt[L];

  const int bx = blockIdx.x;
  if (bx == 0 && threadIdx.x == 0) out[0] = 0.f;   // replaces memset dispatch

  const int b = bx >> 4;
  const int seg = (bx >> 2) & 3;
  const int ch = bx & 3;          // 64-float chunk of H
  const int tid = threadIdx.x;

  const int len = dlen[b];
  if (seg * 256 >= len) return;   // uniform exit, before any barrier
  int segLen = len - seg * 256;
  if (segLen > 256) segLen = 256;

  if (tid < L) cnt[tid] = 0;
  __syncthreads();
  if (tid < segLen) {
    const int l = labels[(size_t)b * T + seg * 256 + tid];
    const int p = atomicAdd(&cnt[l], 1);   // 256 int atomics total: cheap
    idx[l][p] = tid;
  }
  __syncthreads();

  const int l = tid >> 4;         // owned label
  const int cs = tid & 15;        // owned float4 within the 64-float chunk
  const float4* fb4 = (const float4*)feat +
      ((size_t)b * T + seg * 256) * (H / 4) + ch * 16 + cs;

  const int c = cnt[l];
  float4 a = make_float4(0.f, 0.f, 0.f, 0.f);
  int i = 0;
  for (; i + 8 <= c; i += 8) {    // 8 independent loads in flight
    int t8[8];
#pragma unroll
    for (int u = 0; u < 8; ++u) t8[u] = idx[l][i + u];
    float4 f8[8];
#pragma unroll
    for (int u = 0; u < 8; ++u) f8[u] = fb4[(size_t)t8[u] * (H / 4)];
#pragma unroll
    for (int u = 0; u < 8; ++u) {
      a.x += f8[u].x; a.y += f8[u].y; a.z += f8[u].z; a.w += f8[u].w;
    }
  }
  for (; i < c; ++i) {
    const float4 f = fb4[(size_t)idx[l][i] * (H / 4)];
    a.x += f.x; a.y += f.y; a.z += f.z; a.w += f.w;
  }

  *(float4*)(ws_pp + (((size_t)b * 4 + seg) * L + l) * H + ch * 64 + cs * 4) = a;
  if (ch == 0 && tid < L) ws_cntp[(b * 4 + seg) * L + tid] = cnt[tid];
}

// ---------------------------------------------------------------------------
// Kernel 2 (v8): fused dots+loss, R5 algebra (K=2 token sharing, 8 FMA per
// wave-uniform pr ds_read_b128) restored after v7's register-spill disaster
// (v7: 128-reg double buffer under a 128-VGPR cap -> 540 MB scratch traffic).
// Deltas vs R5: finer blocks (1024 x 128thr, 128-token eighths -> better
// length balance, shorter serial staging per block), cb=0 feature batch
// prefetched BEFORE pr staging, explicit ping-pong after. Register audit:
// dot0/dot1 32 + two 4xfloat4 buffers 64 + addr ~= 110 VGPR, no cap, no LDS
// over 25 KB (pr 16K + part 8.7K) -> 6 blk/CU by LDS, 4 by grid.
__global__ __launch_bounds__(128) void dotsloss_kernel(
    const float* __restrict__ feat, const int* __restrict__ dlen,
    const int* __restrict__ labels, const float* __restrict__ ws_pp,
    const int* __restrict__ ws_cntp, float* __restrict__ out) {
  __shared__ float pr[L * H];            // 16 KB prototypes, full H
  __shared__ float part[128][L + 1];     // 8.7 KB padded cross-half partials
  __shared__ int cnts[L];

  const int b = blockIdx.x >> 3;
  const int e = blockIdx.x & 7;          // 128-token eighth
  const int tid = threadIdx.x;

  const int len = dlen[b];
  if (e * 128 >= len) return;            // uniform exit
  const int nseg = (len + 255) >> 8;

  const int ts = tid & 63;
  const int hh = tid >> 6;               // H-half; wave-uniform
  const int t0 = e * 128 + ts;
  const int t1 = t0 + 64;                // always < T: loads safe, masked later

  const float4* fA = (const float4*)(feat + ((size_t)b * T + t0) * H + hh * 128);
  const float4* fB = (const float4*)(feat + ((size_t)b * T + t1) * H + hh * 128);

  // EARLY prefetch of chunk 0 (latency hides under cnts + pr staging)
  float4 fa[4], fb_[4], ga[4], gb[4];
#pragma unroll
  for (int u = 0; u < 4; ++u) { fa[u] = fA[u]; fb_[u] = fB[u]; }

  if (tid < L) {
    const int* cp = ws_cntp + b * 4 * L + tid;
    int c = 0;
    for (int s = 0; s < nseg; ++s) c += cp[s * L];
    cnts[tid] = c;
  }
  __syncthreads();

  // assemble prototypes (full H): sum valid segment partials, divide by count
  const float4* gp4 = (const float4*)(ws_pp + (size_t)b * 4 * L * H);
  for (int i = tid; i < L * H / 4; i += 128) {   // 1024 float4, 8 iters
    const int l = i >> 6;                        // 64 float4 per label row
    float4 s = gp4[i];                           // nseg >= 1 always
    for (int sg = 1; sg < nseg; ++sg) {
      const float4 t2 = gp4[sg * (L * 64) + i];
      s.x += t2.x; s.y += t2.y; s.z += t2.z; s.w += t2.w;
    }
    const int cn = cnts[l];
    const float inv = (cn > 0) ? 1.f / (float)cn : 0.f;
    ((float4*)pr)[i] = make_float4(s.x * inv, s.y * inv, s.z * inv, s.w * inv);
  }
  __syncthreads();

  float dot0[L], dot1[L];
#pragma unroll
  for (int l = 0; l < L; ++l) { dot0[l] = 0.f; dot1[l] = 0.f; }

#define FMA8(FA, FB, CB)                                                    \
  _Pragma("unroll") for (int q4 = 0; q4 < 4; ++q4) {                        \
    _Pragma("unroll") for (int l = 0; l < L; ++l) {                         \
      const float4 p =                                                      \
          *(const float4*)&pr[l * H + hh * 128 + (CB) * 16 + q4 * 4];       \
      dot0[l] += FA[q4].x * p.x + FA[q4].y * p.y +                          \
                 FA[q4].z * p.z + FA[q4].w * p.w;                           \
      dot1[l] += FB[q4].x * p.x + FB[q4].y * p.y +                          \
                 FB[q4].z * p.z + FB[q4].w * p.w;                           \
    }                                                                       \
  }
#define LOAD8(GA, GB, CB)                                                   \
  _Pragma("unroll") for (int u = 0; u < 4; ++u) {                           \
    GA[u] = fA[(CB) * 4 + u];                                               \
    GB[u] = fB[(CB) * 4 + u];                                               \
  }

  // 8 chunks of 16 floats; one batch always in flight
  LOAD8(ga, gb, 1); FMA8(fa, fb_, 0);
  LOAD8(fa, fb_, 2); FMA8(ga, gb, 1);
  LOAD8(ga, gb, 3); FMA8(fa, fb_, 2);
  LOAD8(fa, fb_, 4); FMA8(ga, gb, 3);
  LOAD8(ga, gb, 5); FMA8(fa, fb_, 4);
  LOAD8(fa, fb_, 6); FMA8(ga, gb, 5);
  LOAD8(ga, gb, 7); FMA8(fa, fb_, 6);
  FMA8(ga, gb, 7);
#undef FMA8
#undef LOAD8

  // cross-half combine: hh=1 publishes, hh=0 finishes
  if (hh == 1) {
#pragma unroll
    for (int l = 0; l < L; ++l) {
      part[ts][l] = dot0[l];
      part[ts + 64][l] = dot1[l];
    }
  }
  __syncthreads();

  if (hh == 0) {
    float tok = 0.f;
#pragma unroll
    for (int k = 0; k < 2; ++k) {
      const int t = t0 + k * 64;
      if (t < len) {
        float lg[L];
#pragma unroll
        for (int l = 0; l < L; ++l) {
          const float d = (k == 0 ? dot0[l] : dot1[l]) + part[ts + k * 64][l];
          lg[l] = (cnts[l] > 0) ? d * INV_TEMP : NEG_INF;
        }
        float m = lg[0];
#pragma unroll
        for (int l = 1; l < L; ++l) m = fmaxf(m, lg[l]);
        float se = 0.f;
#pragma unroll
        for (int l = 0; l < L; ++l) se += expf(lg[l] - m);
        const float lsp = m + logf(se);

        const int lab = labels[(size_t)b * T + t];
        float pos = 0.f;
#pragma unroll
        for (int l = 0; l < L; ++l) pos += (l == lab) ? lg[l] : 0.f;

        tok += lsp - pos;
      }
    }
    // wave-0 shuffle reduction; single atomic per block
#pragma unroll
    for (int off = 32; off > 0; off >>= 1) tok += __shfl_down(tok, off, 64);
    if (ts == 0) atomicAdd(out, tok / ((float)len * (float)B));
  }
}

extern "C" void kernel_launch(void* const* d_in, const int* in_sizes, int n_in,
                              void* d_out, int out_size, void* d_ws, size_t ws_size,
                              hipStream_t stream) {
  const float* feat = (const float*)d_in[0];
  const int* dlen = (const int*)d_in[1];
  const int* labels = (const int*)d_in[2];
  float* out = (float*)d_out;

  float* ws_pp = (float*)d_ws;                           // B*4*L*H floats
  int* ws_cntp = (int*)(ws_pp + (size_t)B * 4 * L * H);  // B*4*L ints

  proto_kernel<<<B * 16, 256, 0, stream>>>(feat, dlen, labels, ws_pp,
                                           ws_cntp, out);
  dotsloss_kernel<<<B * 8, 128, 0, stream>>>(feat, dlen, labels, ws_pp,
                                             ws_cntp, out);
}

// Round 9
// 213.720 us; speedup vs baseline: 1.9222x; 1.2682x over previous
//
#include <hip/hip_runtime.h>
#include <math.h>

#define B 128
#define T 1024
#define H 256
#define L 16
#define INV_TEMP (1.0f/0.07f)
#define NEG_INF -1e30f

// ws layout:
//   ws_proto : float[B][L][H]   FINAL prototypes (divided)   2 MB
//   ws_cnt   : int[B][L]        final label counts           8 KB

// ---------------------------------------------------------------------------
// Kernel 1 (v9): finalizing gather. Block = (b, 64-float H-chunk); counting-
// sorts ALL len tokens into ushort idx lists (32 KB), then thread (l, cs)
// gathers cnt[l] member rows and writes the FINAL divided prototype.
// Deletes the per-seg partials (8 MB ws write + consumer nseg-sum) and the
// 4x-redundant idx builds of v5. grid = B*4 = 512 blocks, 256 thr.
__global__ __launch_bounds__(256) void proto_kernel(
    const float* __restrict__ feat, const int* __restrict__ dlen,
    const int* __restrict__ labels, float* __restrict__ ws_proto,
    int* __restrict__ ws_cnt, float* __restrict__ out) {
  __shared__ unsigned short idx[L][T];   // 32 KB token lists per label
  __shared__ int cnt[L];

  const int bx = blockIdx.x;
  if (bx == 0 && threadIdx.x == 0) out[0] = 0.f;   // replaces memset dispatch

  const int b = bx >> 2;
  const int ch = bx & 3;          // 64-float chunk of H
  const int tid = threadIdx.x;
  const int len = dlen[b];        // >= 1 always

  if (tid < L) cnt[tid] = 0;
  __syncthreads();
  for (int t = tid; t < len; t += 256) {
    const int l = labels[(size_t)b * T + t];
    const int p = atomicAdd(&cnt[l], 1);   // <=1024 int atomics: cheap
    idx[l][p] = (unsigned short)t;
  }
  __syncthreads();

  const int l = tid >> 4;         // owned label
  const int cs = tid & 15;        // owned float4 within the 64-float chunk
  const float4* fb4 = (const float4*)feat +
      (size_t)b * T * (H / 4) + ch * 16 + cs;

  const int c = cnt[l];
  float4 a = make_float4(0.f, 0.f, 0.f, 0.f);
  int i = 0;
  for (; i + 8 <= c; i += 8) {    // 8 independent loads in flight
    int t8[8];
#pragma unroll
    for (int u = 0; u < 8; ++u) t8[u] = idx[l][i + u];
    float4 f8[8];
#pragma unroll
    for (int u = 0; u < 8; ++u) f8[u] = fb4[(size_t)t8[u] * (H / 4)];
#pragma unroll
    for (int u = 0; u < 8; ++u) {
      a.x += f8[u].x; a.y += f8[u].y; a.z += f8[u].z; a.w += f8[u].w;
    }
  }
  for (; i < c; ++i) {
    const float4 f = fb4[(size_t)idx[l][i] * (H / 4)];
    a.x += f.x; a.y += f.y; a.z += f.z; a.w += f.w;
  }

  const float inv = (c > 0) ? 1.f / (float)c : 0.f;
  a.x *= inv; a.y *= inv; a.z *= inv; a.w *= inv;
  *(float4*)(ws_proto + ((size_t)b * L + l) * H + ch * 64 + cs * 4) = a;
  if (ch == 0 && tid < L) ws_cnt[b * L + tid] = cnt[tid];
}

// ---------------------------------------------------------------------------
// Kernel 2 (v9): fused dots+loss — R5's proven hot loop VERBATIM (K=2 token
// sharing, compiler-scheduled `unroll 2`, no early prefetch, no manual
// ping-pong: both spill-free at ~52-80 VGPR). Only deltas vs R5: prototype
// staging is now a pure 16 KB copy (protos pre-divided), cnts a direct load,
// and part padded to L+1 (kills the 2-bank write conflict).
__global__ __launch_bounds__(256) void dotsloss_kernel(
    const float* __restrict__ feat, const int* __restrict__ dlen,
    const int* __restrict__ labels, const float* __restrict__ ws_proto,
    const int* __restrict__ ws_cnt, float* __restrict__ out) {
  __shared__ float pr[L * H];          // 16 KB prototypes, full H
  __shared__ float part[256][L + 1];   // 17.4 KB padded cross-half partials
  __shared__ int cnts[L];
  __shared__ float red[256];

  const int b = blockIdx.x >> 2;
  const int q = blockIdx.x & 3;        // 256-token quarter
  const int tid = threadIdx.x;

  const int len = dlen[b];
  if (q * 256 >= len) return;          // uniform exit

  if (tid < L) cnts[tid] = ws_cnt[b * L + tid];
  __syncthreads();

  // stage prototypes: pure copy, 4 iters of float4
  const float4* gp4 = (const float4*)(ws_proto + (size_t)b * L * H);
  for (int i = tid; i < L * H / 4; i += 256) ((float4*)pr)[i] = gp4[i];
  __syncthreads();

  const int ts = tid & 127;
  const int hh = tid >> 7;             // H-half; constant within each wave
  const int t0 = q * 256 + ts;
  const int t1 = t0 + 128;             // always < T: loads safe, value masked

  const float4* fA = (const float4*)feat + ((size_t)b * T + t0) * (H / 4) + hh * 32;
  const float4* fB = (const float4*)feat + ((size_t)b * T + t1) * (H / 4) + hh * 32;

  float dot0[L], dot1[L];
#pragma unroll
  for (int l = 0; l < L; ++l) { dot0[l] = 0.f; dot1[l] = 0.f; }

#pragma unroll 2
  for (int cb = 0; cb < 8; ++cb) {   // 16-float chunks of this 128-float half
    float4 fa[4], fb_[4];
#pragma unroll
    for (int q4 = 0; q4 < 4; ++q4) {
      fa[q4] = fA[cb * 4 + q4];
      fb_[q4] = fB[cb * 4 + q4];
    }
#pragma unroll
    for (int q4 = 0; q4 < 4; ++q4) {
#pragma unroll
      for (int l = 0; l < L; ++l) {
        const float4 p = *(const float4*)&pr[l * H + hh * 128 + cb * 16 + q4 * 4];
        dot0[l] += fa[q4].x * p.x + fa[q4].y * p.y +
                   fa[q4].z * p.z + fa[q4].w * p.w;
        dot1[l] += fb_[q4].x * p.x + fb_[q4].y * p.y +
                   fb_[q4].z * p.z + fb_[q4].w * p.w;
      }
    }
  }

  if (hh == 1) {
#pragma unroll
    for (int l = 0; l < L; ++l) {
      part[ts][l] = dot0[l];
      part[ts + 128][l] = dot1[l];
    }
  }
  __syncthreads();

  float tok = 0.f;
  if (hh == 0) {
#pragma unroll
    for (int k = 0; k < 2; ++k) {
      const int t = t0 + k * 128;
      if (t < len) {
        float lg[L];
#pragma unroll
        for (int l = 0; l < L; ++l) {
          const float d = (k == 0 ? dot0[l] : dot1[l]) + part[ts + k * 128][l];
          lg[l] = (cnts[l] > 0) ? d * INV_TEMP : NEG_INF;
        }
        float m = lg[0];
#pragma unroll
        for (int l = 1; l < L; ++l) m = fmaxf(m, lg[l]);
        float se = 0.f;
#pragma unroll
        for (int l = 0; l < L; ++l) se += expf(lg[l] - m);
        const float lsp = m + logf(se);

        const int lab = labels[(size_t)b * T + t];
        float pos = 0.f;
#pragma unroll
        for (int l = 0; l < L; ++l) pos += (l == lab) ? lg[l] : 0.f;

        tok += lsp - pos;
      }
    }
  }

  red[tid] = tok;
  __syncthreads();
#pragma unroll
  for (int s = 128; s > 0; s >>= 1) {
    if (tid < s) red[tid] += red[tid + s];
    __syncthreads();
  }
  if (tid == 0) atomicAdd(out, red[0] / ((float)len * (float)B));
}

extern "C" void kernel_launch(void* const* d_in, const int* in_sizes, int n_in,
                              void* d_out, int out_size, void* d_ws, size_t ws_size,
                              hipStream_t stream) {
  const float* feat = (const float*)d_in[0];
  const int* dlen = (const int*)d_in[1];
  const int* labels = (const int*)d_in[2];
  float* out = (float*)d_out;

  float* ws_proto = (float*)d_ws;                          // B*L*H floats
  int* ws_cnt = (int*)(ws_proto + (size_t)B * L * H);      // B*L ints

  proto_kernel<<<B * 4, 256, 0, stream>>>(feat, dlen, labels, ws_proto,
                                          ws_cnt, out);
  dotsloss_kernel<<<B * 4, 256, 0, stream>>>(feat, dlen, labels, ws_proto,
                                             ws_cnt, out);
}